// Round 1
// baseline (609.469 us; speedup 1.0000x reference)
//
#include <hip/hip_runtime.h>
#include <math.h>
#include <stdint.h>

// ChunkedSelfAttention: B=4, L=4096, H=16, DH=DV=128, CHUNK=1024, causal in-chunk.
// Strategy: bf16 MFMA flash attention per chunk.
//   pre-pass 1: rope(q)*scale*log2e, rope(k) -> bf16 ws, layout (b,n,h,ck,dh)
//   pre-pass 2: v -> bf16 V^T ws, layout (b,n,h,dv,ck)
//   attention:  S^T = K.Q^T (32x32x16), softmax in-register (exp2 domain),
//               O^T += V^T.P^T (32x32x8 _1k) -- S^T D-frag == P^T B-frag (no shuffles)

typedef __attribute__((ext_vector_type(8)))  short bf16x8;
typedef __attribute__((ext_vector_type(4)))  short bf16x4;
typedef __attribute__((ext_vector_type(16))) float f32x16;
typedef __attribute__((ext_vector_type(4)))  float f32x4;
typedef __attribute__((ext_vector_type(4)))  unsigned short us4;

__device__ __forceinline__ unsigned short f2bf(float x) {  // RNE fp32->bf16
  unsigned u = __float_as_uint(x);
  u += 0x7fff + ((u >> 16) & 1);
  return (unsigned short)(u >> 16);
}

// ---------------- RoPE + scale + bf16 cast for Q and K ----------------
// one wave per (b,l,h) row; lane i handles dh pair (i, i+64)
__global__ __launch_bounds__(256) void rope_kernel(
    const float* __restrict__ q, const float* __restrict__ k,
    unsigned short* __restrict__ qws, unsigned short* __restrict__ kws)
{
  const int w    = threadIdx.x >> 6;
  const int lane = threadIdx.x & 63;
  const int r    = blockIdx.x * 4 + w;   // row over (b,l,h); L*H = 65536
  const int b    = r >> 16;
  const int rem  = r & 65535;
  const int l    = rem >> 4;
  const int h    = rem & 15;
  // freq = 10000^(-lane/64) = exp2(lane * -log2(10000)/64)
  const float freq  = __builtin_amdgcn_exp2f((float)lane * -0.20762050593046014f);
  const float angle = (float)l * freq;
  float sn, cs;
  sincosf(angle, &sn, &cs);
  const size_t src = (size_t)r * 128 + lane;
  const int n = l >> 10, ck = l & 1023;
  const size_t dst = ((((size_t)b * 4 + n) * 16 + h) * 1024 + ck) * 128 + lane;
  const float QS = 0.12751741f;  // (1/sqrt(128)) * log2(e): S^T lands in exp2 domain
  float x1 = q[src], x2 = q[src + 64];
  qws[dst]      = f2bf((x1 * cs - x2 * sn) * QS);
  qws[dst + 64] = f2bf((x2 * cs + x1 * sn) * QS);
  x1 = k[src]; x2 = k[src + 64];
  kws[dst]      = f2bf(x1 * cs - x2 * sn);
  kws[dst + 64] = f2bf(x2 * cs + x1 * sn);
}

// ---------------- V -> bf16 V^T, layout (b,n,h,dv,ck) ----------------
// block per (b,n,h, 64-row l-slab); LDS-tiled transpose
__global__ __launch_bounds__(256) void vtrans_kernel(
    const float* __restrict__ v, unsigned short* __restrict__ vtws)
{
  __shared__ unsigned short tile[128 * 72];  // [dv][ck], stride 72 (144 B, 16B-mult)
  const int t   = threadIdx.x;
  const int ckb = blockIdx.x & 15;
  const int h   = (blockIdx.x >> 4) & 15;
  const int n   = (blockIdx.x >> 8) & 3;
  const int b   = blockIdx.x >> 10;
  const int i0  = (t >> 4) * 4;      // l within slab: 4 rows
  const int dv0 = (t & 15) * 8;      // 8 dv
  const int l0  = n * 1024 + ckb * 64;
  const float* src = v + (((size_t)b * 4096 + l0) * 16 + h) * 128;
  unsigned short vals[4][8];
#pragma unroll
  for (int i = 0; i < 4; ++i) {
    const float* p = src + (size_t)(i0 + i) * 2048 + dv0;  // l stride = H*DV
    f32x4 a = *(const f32x4*)p;
    f32x4 c = *(const f32x4*)(p + 4);
#pragma unroll
    for (int jj = 0; jj < 4; ++jj) { vals[i][jj] = f2bf(a[jj]); vals[i][4 + jj] = f2bf(c[jj]); }
  }
#pragma unroll
  for (int dd = 0; dd < 8; ++dd) {
    us4 pk = { vals[0][dd], vals[1][dd], vals[2][dd], vals[3][dd] };
    *(us4*)&tile[(dv0 + dd) * 72 + i0] = pk;  // ds_write_b64, 8B aligned
  }
  __syncthreads();
  const int dv = t >> 1, hf = t & 1;
  const size_t dstb = ((((size_t)b * 4 + n) * 16 + h) * 128 + dv) * 1024 + ckb * 64 + hf * 32;
  const unsigned short* sl = &tile[dv * 72 + hf * 32];
#pragma unroll
  for (int kk = 0; kk < 4; ++kk)
    *(uint4*)(vtws + dstb + kk * 8) = *(const uint4*)(sl + kk * 8);
}

// ---------------- flash attention over one chunk ----------------
// grid (qt=8, n*h=64, b=4); block 256 = 4 waves; wave owns 32 q-rows.
__global__ __launch_bounds__(256) void attn_kernel(
    const unsigned short* __restrict__ qws, const unsigned short* __restrict__ kws,
    const unsigned short* __restrict__ vtws, float* __restrict__ out)
{
  __shared__ unsigned short smem[64 * 136 + 128 * 72];  // 35840 B
  unsigned short* kt = smem;             // K tile [64 kv][136] (128 dh + 8 pad)
  unsigned short* vt = smem + 64 * 136;  // V^T tile [128 dv][72] (64 ck + 8 pad)
  unsigned short* qstage = smem;         // Q tile [128][136], prologue only (fits)

  const int qt   = blockIdx.x;
  const int nh   = blockIdx.y;
  const int b    = blockIdx.z;
  const int t    = threadIdx.x;
  const int lane = t & 63;
  const int w    = t >> 6;
  const int c    = lane & 31;   // q index for S^T/O^T frags
  const int g    = lane >> 5;

  const size_t bnh = (size_t)b * 64 + nh;
  const unsigned short* qbase = qws + bnh * (1024 * 128) + (size_t)qt * (128 * 128);
  const unsigned short* kbase = kws + bnh * (1024 * 128);
  const unsigned short* vbase = vtws + bnh * (128 * 1024);

  // ---- stage Q tile (32 KB contiguous) into LDS, pull B-frags, then free LDS
#pragma unroll
  for (int it = 0; it < 8; ++it) {
    int u = it * 256 + t;
    int row = u >> 4, col = u & 15;
    uint4 val = ((const uint4*)qbase)[u];
    *(uint4*)((char*)qstage + row * 272 + col * 16) = val;
  }
  __syncthreads();
  const int qsub = w * 32;
  bf16x8 qf[8];  // B-frag f: q = qsub+c, dh = 16f + 8g + j
  {
    const char* qp = (const char*)qstage + (qsub + c) * 272 + g * 16;
#pragma unroll
    for (int f = 0; f < 8; ++f) qf[f] = *(const bf16x8*)(qp + f * 32);
  }
  __syncthreads();

  f32x16 acc[4] = {};            // O^T: acc[d] = dv [32d,32d+32) x q; col=c=q
  float m_run = -INFINITY, l_run = 0.0f;
  const int q0w  = qt * 128 + qsub;
  const int rowq = q0w + c;      // this lane's q row (chunk-local)
  const int jmax = 2 * qt + 2;

  for (int j = 0; j < jmax; ++j) {
    // ---- stage K (16 KB contiguous) and V^T (128B x 128 rows) tiles
    const uint4* kg = (const uint4*)(kbase + (size_t)j * (64 * 128));
#pragma unroll
    for (int it = 0; it < 4; ++it) {
      int u = it * 256 + t;
      int row = u >> 4, col = u & 15;
      uint4 val = kg[u];
      *(uint4*)((char*)kt + row * 272 + col * 16) = val;
    }
#pragma unroll
    for (int it = 0; it < 4; ++it) {
      int u = it * 256 + t;
      int dv = u >> 3, col = u & 7;
      uint4 val = *(const uint4*)(vbase + (size_t)dv * 1024 + j * 64 + col * 8);
      *(uint4*)((char*)vt + dv * 144 + col * 16) = val;
    }
    __syncthreads();

    const int kv0 = j * 64;
    if (kv0 <= q0w + 31) {  // not fully masked for this wave
      // ---- S^T = K . Q^T : two 32(kv) x 32(q) tiles
      f32x16 s[2];
#pragma unroll
      for (int ks = 0; ks < 2; ++ks) {
        f32x16 a = {};
        const char* kp = (const char*)kt + (ks * 32 + c) * 272 + g * 16;
#pragma unroll
        for (int f = 0; f < 8; ++f) {
          bf16x8 kf = *(const bf16x8*)(kp + f * 32);  // A: kv=ks*32+c, dh=16f+8g+j
          a = __builtin_amdgcn_mfma_f32_32x32x16_bf16(kf, qf[f], a, 0, 0, 0);
        }
        s[ks] = a;
      }
      // ---- online softmax (exp2 domain; scale*log2e folded into Q)
      const bool needmask = (kv0 + 63) > q0w;
      float mloc = -INFINITY;
      if (needmask) {
#pragma unroll
        for (int ks = 0; ks < 2; ++ks)
#pragma unroll
          for (int r = 0; r < 16; ++r) {
            int kv = kv0 + ks * 32 + (r & 3) + 8 * (r >> 2) + 4 * g;
            float val = (kv > rowq) ? -3.0e38f : s[ks][r];
            s[ks][r] = val;
            mloc = fmaxf(mloc, val);
          }
      } else {
#pragma unroll
        for (int ks = 0; ks < 2; ++ks)
#pragma unroll
          for (int r = 0; r < 16; ++r) mloc = fmaxf(mloc, s[ks][r]);
      }
      mloc = fmaxf(mloc, __shfl_xor(mloc, 32));  // both g-halves hold q=c
      const float mnew  = fmaxf(m_run, mloc);
      const float alpha = __builtin_amdgcn_exp2f(m_run - mnew);
      float rsum = 0.0f;
#pragma unroll
      for (int ks = 0; ks < 2; ++ks)
#pragma unroll
        for (int r = 0; r < 16; ++r) {
          float p = __builtin_amdgcn_exp2f(s[ks][r] - mnew);
          s[ks][r] = p;
          rsum += p;
        }
      rsum += __shfl_xor(rsum, 32);
      l_run = l_run * alpha + rsum;
      m_run = mnew;
#pragma unroll
      for (int d = 0; d < 4; ++d)
#pragma unroll
        for (int r = 0; r < 16; ++r) acc[d][r] *= alpha;
      // ---- pack P^T frags: S^T D-regs 4o..4o+3 ARE the 32x32x8 B-frag (k=4g+j)
      bf16x4 pfr[8];
#pragma unroll
      for (int o = 0; o < 8; ++o) {
        const int ks = o >> 2, rb = 4 * (o & 3);
        unsigned u0 = __float_as_uint(s[ks][rb + 0]); u0 += 0x7fff + ((u0 >> 16) & 1);
        unsigned u1 = __float_as_uint(s[ks][rb + 1]); u1 += 0x7fff + ((u1 >> 16) & 1);
        unsigned u2 = __float_as_uint(s[ks][rb + 2]); u2 += 0x7fff + ((u2 >> 16) & 1);
        unsigned u3 = __float_as_uint(s[ks][rb + 3]); u3 += 0x7fff + ((u3 >> 16) & 1);
        union { unsigned uu[2]; bf16x4 bv; } pk;
        pk.uu[0] = __builtin_amdgcn_perm(u1, u0, 0x07060302u);
        pk.uu[1] = __builtin_amdgcn_perm(u3, u2, 0x07060302u);
        pfr[o] = pk.bv;
      }
      // ---- O^T += V^T . P^T   (A: dv=32d+c, kv=8o+4g+j from LDS b64)
      const char* vp = (const char*)vt + c * 144 + g * 8;
#pragma unroll
      for (int d = 0; d < 4; ++d) {
        f32x16 a = acc[d];
        const char* vpd = vp + d * 32 * 144;
#pragma unroll
        for (int o = 0; o < 8; ++o) {
          bf16x4 vf = *(const bf16x4*)(vpd + o * 16);
          a = __builtin_amdgcn_mfma_f32_32x32x8bf16_1k(vf, pfr[o], a, 0, 0, 0);
        }
        acc[d] = a;
      }
    }
    __syncthreads();
  }

  // ---- epilogue: O = O^T/l ; lane holds q=rowq, dv = 32d + 8e + 4g + rr
  const float invl = 1.0f / l_run;
  const int n = nh >> 4, h = nh & 15;
  const size_t orow = (((size_t)b * 4096 + n * 1024 + rowq) * 16 + h) * 128;
#pragma unroll
  for (int d = 0; d < 4; ++d)
#pragma unroll
    for (int e = 0; e < 4; ++e) {
      f32x4 vv;
#pragma unroll
      for (int rr = 0; rr < 4; ++rr) vv[rr] = acc[d][4 * e + rr] * invl;
      *(f32x4*)(out + orow + 32 * d + 8 * e + 4 * g) = vv;
    }
}

extern "C" void kernel_launch(void* const* d_in, const int* in_sizes, int n_in,
                              void* d_out, int out_size, void* d_ws, size_t ws_size,
                              hipStream_t stream) {
  const float* q = (const float*)d_in[0];
  const float* k = (const float*)d_in[1];
  const float* v = (const float*)d_in[2];
  float* out = (float*)d_out;
  // ws: qws | kws | vtws, each 4*4096*16*128 bf16 = 64 MB (192 MB total)
  unsigned short* qws  = (unsigned short*)d_ws;
  unsigned short* kws  = qws + (size_t)33554432;
  unsigned short* vtws = kws + (size_t)33554432;

  rope_kernel<<<65536, 256, 0, stream>>>(q, k, qws, kws);
  vtrans_kernel<<<4096, 256, 0, stream>>>(v, vtws);
  attn_kernel<<<dim3(8, 64, 4), 256, 0, stream>>>(qws, kws, vtws, out);
}